// Round 3
// baseline (270.578 us; speedup 1.0000x reference)
//
#include <hip/hip_runtime.h>

typedef __bf16 bf16x8 __attribute__((ext_vector_type(8)));
typedef float floatx4 __attribute__((ext_vector_type(4)));
typedef unsigned short u16;
typedef unsigned int u32;

#define T_SEQ 4096
#define DIM 64
#define QT 64    // Q rows per block (16 per wave)
#define KT 64    // K rows per iteration
#define LDSP 72  // LDS row stride in u16 (144 B = 9*16B: aligned, 2-way banks max)
#define NEG_BIG (-1e30f)

__device__ __forceinline__ u16 f2bf(float f) {
  u32 u = __builtin_bit_cast(u32, f);
  u += 0x7fff + ((u >> 16) & 1);
  return (u16)(u >> 16);
}
__device__ __forceinline__ float bf2f(u16 h) {
  u32 u = ((u32)h) << 16;
  return __builtin_bit_cast(float, u);
}
__device__ __forceinline__ void split2(float x, u16& hi, u16& lo) {
  hi = f2bf(x);
  lo = f2bf(x - bf2f(hi));
}

union B8 { bf16x8 v; u16 u[8]; };

__launch_bounds__(256, 1)
__global__ void attn_kernel(const float* __restrict__ X, const float* __restrict__ W,
                            float* __restrict__ out) {
  // 64512 bytes total
  __shared__ __attribute__((aligned(16))) u16 Qsh[QT * LDSP];   // Q hi (bf16)
  __shared__ __attribute__((aligned(16))) u16 Qsl[QT * LDSP];   // Q lo
  __shared__ __attribute__((aligned(16))) u16 Ksh[KT * LDSP];   // K hi
  __shared__ __attribute__((aligned(16))) u16 Ksl[KT * LDSP];   // K lo
  __shared__ __attribute__((aligned(16))) u16 Vt[DIM * LDSP];   // V^T hi
  __shared__ __attribute__((aligned(16))) u16 WtPs[2 * DIM * LDSP]; // Wt hi|lo, later P

  u16* Wth = WtPs;
  u16* Wtl = WtPs + DIM * LDSP;
  u16* Ps  = WtPs;  // safe alias: Wt reads all precede (2 barriers) first Ps write

  const int tid = threadIdx.x;
  const int lane = tid & 63;
  const int wave = tid >> 6;
  const int quad = lane >> 4;
  const int ln = lane & 15;
  const int b = blockIdx.y;
  const int q0 = blockIdx.x * QT;
  const long bbase = (long)b * T_SEQ * DIM;
  const int wq = wave * 16;  // this wave's Q-row base within tile

  // ---- stage Wt = W^T split to bf16 hi/lo ----
  {
    int d = tid >> 2, e0 = (tid & 3) * 16;
#pragma unroll
    for (int j = 0; j < 16; j++) {
      u16 hi, lo;
      split2(W[d * DIM + e0 + j], hi, lo);
      Wth[(e0 + j) * LDSP + d] = hi;
      Wtl[(e0 + j) * LDSP + d] = lo;
    }
  }
  __syncthreads();

  // ---- Q = X @ W (3-term split MFMA), write split bf16 Q to LDS ----
  {
    floatx4 acc[4];
#pragma unroll
    for (int ct = 0; ct < 4; ct++) acc[ct] = (floatx4)0.0f;
#pragma unroll
    for (int ks = 0; ks < 2; ks++) {
      const float* px = X + bbase + (long)(q0 + wq + ln) * DIM + ks * 32 + quad * 8;
      float4 xa = *(const float4*)px;
      float4 xb = *(const float4*)(px + 4);
      B8 aXh, aXl;
      float xs[8] = {xa.x, xa.y, xa.z, xa.w, xb.x, xb.y, xb.z, xb.w};
#pragma unroll
      for (int j = 0; j < 8; j++) split2(xs[j], aXh.u[j], aXl.u[j]);
#pragma unroll
      for (int ct = 0; ct < 4; ct++) {
        bf16x8 bWh = *(const bf16x8*)&Wth[(ct * 16 + ln) * LDSP + ks * 32 + quad * 8];
        bf16x8 bWl = *(const bf16x8*)&Wtl[(ct * 16 + ln) * LDSP + ks * 32 + quad * 8];
        acc[ct] = __builtin_amdgcn_mfma_f32_16x16x32_bf16(aXh.v, bWh, acc[ct], 0, 0, 0);
        acc[ct] = __builtin_amdgcn_mfma_f32_16x16x32_bf16(aXh.v, bWl, acc[ct], 0, 0, 0);
        acc[ct] = __builtin_amdgcn_mfma_f32_16x16x32_bf16(aXl.v, bWh, acc[ct], 0, 0, 0);
      }
    }
#pragma unroll
    for (int ct = 0; ct < 4; ct++)
#pragma unroll
      for (int r = 0; r < 4; r++) {
        u16 hi, lo;
        split2(acc[ct][r], hi, lo);
        Qsh[(wq + quad * 4 + r) * LDSP + ct * 16 + ln] = hi;
        Qsl[(wq + quad * 4 + r) * LDSP + ct * 16 + ln] = lo;
      }
  }

  // ---- online softmax state + O accumulator ----
  float mrow[4], lrow[4];
  floatx4 O[4];
#pragma unroll
  for (int r = 0; r < 4; r++) { mrow[r] = NEG_BIG; lrow[r] = 0.0f; }
#pragma unroll
  for (int cd = 0; cd < 4; cd++) O[cd] = (floatx4)0.0f;

  for (int kt = 0; kt < T_SEQ / KT; kt++) {
    __syncthreads();  // prior iter's LDS reads done (also fences Wt reads on iter 0)
    // ---- stage K tile split hi/lo + transposed V (hi) ----
    {
      int kk = tid >> 2, c0 = (tid & 3) * 16;
      const float4* src = (const float4*)(X + bbase + (long)(kt * KT + kk) * DIM + c0);
      union { u16 u[16]; uint4 q[2]; } hi, lo;
#pragma unroll
      for (int i = 0; i < 4; i++) {
        float4 v = src[i];
        split2(v.x, hi.u[i * 4 + 0], lo.u[i * 4 + 0]);
        split2(v.y, hi.u[i * 4 + 1], lo.u[i * 4 + 1]);
        split2(v.z, hi.u[i * 4 + 2], lo.u[i * 4 + 2]);
        split2(v.w, hi.u[i * 4 + 3], lo.u[i * 4 + 3]);
      }
      *(uint4*)&Ksh[kk * LDSP + c0] = hi.q[0];
      *(uint4*)&Ksh[kk * LDSP + c0 + 8] = hi.q[1];
      *(uint4*)&Ksl[kk * LDSP + c0] = lo.q[0];
      *(uint4*)&Ksl[kk * LDSP + c0 + 8] = lo.q[1];
#pragma unroll
      for (int j = 0; j < 16; j++) Vt[(c0 + j) * LDSP + kk] = hi.u[j];
    }
    __syncthreads();

    // ---- S = Q @ K^T, 3-term split (16 rows x 64 cols per wave) ----
    floatx4 S[4];
#pragma unroll
    for (int ct = 0; ct < 4; ct++) S[ct] = (floatx4)0.0f;
#pragma unroll
    for (int ks = 0; ks < 2; ks++) {
      bf16x8 aQh = *(const bf16x8*)&Qsh[(wq + ln) * LDSP + ks * 32 + quad * 8];
      bf16x8 aQl = *(const bf16x8*)&Qsl[(wq + ln) * LDSP + ks * 32 + quad * 8];
#pragma unroll
      for (int ct = 0; ct < 4; ct++) {
        bf16x8 bKh = *(const bf16x8*)&Ksh[(ct * 16 + ln) * LDSP + ks * 32 + quad * 8];
        bf16x8 bKl = *(const bf16x8*)&Ksl[(ct * 16 + ln) * LDSP + ks * 32 + quad * 8];
        S[ct] = __builtin_amdgcn_mfma_f32_16x16x32_bf16(aQh, bKh, S[ct], 0, 0, 0);
        S[ct] = __builtin_amdgcn_mfma_f32_16x16x32_bf16(aQh, bKl, S[ct], 0, 0, 0);
        S[ct] = __builtin_amdgcn_mfma_f32_16x16x32_bf16(aQl, bKh, S[ct], 0, 0, 0);
      }
    }

    // ---- online softmax (row = quad*4 + r, col = ct*16 + ln) ----
    float nm[4];
#pragma unroll
    for (int r = 0; r < 4; r++)
      nm[r] = fmaxf(fmaxf(S[0][r], S[1][r]), fmaxf(S[2][r], S[3][r]));
#pragma unroll
    for (int mask = 1; mask < 16; mask <<= 1)
#pragma unroll
      for (int r = 0; r < 4; r++) nm[r] = fmaxf(nm[r], __shfl_xor(nm[r], mask, 64));
    float al[4];
#pragma unroll
    for (int r = 0; r < 4; r++) {
      float mn = fmaxf(mrow[r], nm[r]);
      al[r] = __expf(mrow[r] - mn);
      mrow[r] = mn;
    }
    float rs[4] = {0.f, 0.f, 0.f, 0.f};
#pragma unroll
    for (int ct = 0; ct < 4; ct++)
#pragma unroll
      for (int r = 0; r < 4; r++) {
        float p = __expf(S[ct][r] - mrow[r]);
        S[ct][r] = p;
        rs[r] += p;
      }
#pragma unroll
    for (int mask = 1; mask < 16; mask <<= 1)
#pragma unroll
      for (int r = 0; r < 4; r++) rs[r] += __shfl_xor(rs[r], mask, 64);
#pragma unroll
    for (int r = 0; r < 4; r++) lrow[r] = lrow[r] * al[r] + rs[r];
    // write P (bf16) to wave-private LDS rows
#pragma unroll
    for (int ct = 0; ct < 4; ct++)
#pragma unroll
      for (int r = 0; r < 4; r++)
        Ps[(wq + quad * 4 + r) * LDSP + ct * 16 + ln] = f2bf(S[ct][r]);
    // rescale O
#pragma unroll
    for (int cd = 0; cd < 4; cd++)
#pragma unroll
      for (int r = 0; r < 4; r++) O[cd][r] *= al[r];

    __syncthreads();  // P writes visible before PV reads (correctness-first)

    // ---- O += P @ V ----
#pragma unroll
    for (int ks = 0; ks < 2; ks++) {
      bf16x8 aP = *(const bf16x8*)&Ps[(wq + ln) * LDSP + ks * 32 + quad * 8];
#pragma unroll
      for (int cd = 0; cd < 4; cd++) {
        bf16x8 bV = *(const bf16x8*)&Vt[(cd * 16 + ln) * LDSP + ks * 32 + quad * 8];
        O[cd] = __builtin_amdgcn_mfma_f32_16x16x32_bf16(aP, bV, O[cd], 0, 0, 0);
      }
    }
  }

  // ---- epilogue: out = O / l (fp32 output) ----
#pragma unroll
  for (int cd = 0; cd < 4; cd++)
#pragma unroll
    for (int r = 0; r < 4; r++) {
      long row = q0 + wq + quad * 4 + r;
      out[bbase + row * DIM + cd * 16 + ln] = O[cd][r] / lrow[r];
    }
}

extern "C" void kernel_launch(void* const* d_in, const int* in_sizes, int n_in,
                              void* d_out, int out_size, void* d_ws, size_t ws_size,
                              hipStream_t stream) {
  const float* X = (const float*)d_in[0];
  const float* W = (const float*)d_in[1];
  float* out = (float*)d_out;
  dim3 grid(T_SEQ / QT, 8);
  attn_kernel<<<grid, 256, 0, stream>>>(X, W, out);
}

// Round 4
// 146.028 us; speedup vs baseline: 1.8529x; 1.8529x over previous
//
#include <hip/hip_runtime.h>

typedef _Float16 f16;
typedef _Float16 f16x8 __attribute__((ext_vector_type(8)));
typedef __bf16 bf16x8 __attribute__((ext_vector_type(8)));
typedef float floatx4 __attribute__((ext_vector_type(4)));
typedef unsigned short u16;
typedef unsigned int u32;

#define B_N   8
#define T_SEQ 4096
#define DIM   64
#define QT    64    // q rows per block
#define KT    128   // keys per iter (32 per wave)
#define PSTR  40    // P row stride (80 B: 16B-aligned rows)
#define OSTR  68    // epilogue O row stride (fp32)

__device__ __forceinline__ u16 f2bf(float f) {
  u32 u = __builtin_bit_cast(u32, f);
  u += 0x7fff + ((u >> 16) & 1);
  return (u16)(u >> 16);
}

// ---------------- prep: Kh=f16(X), Qh=f16(X@W), Vt=bf16(X^T) ----------------
__launch_bounds__(256, 2)
__global__ void prep_kernel(const float* __restrict__ X, const float* __restrict__ W,
                            u16* __restrict__ Kh, u16* __restrict__ Qh,
                            u16* __restrict__ Vt) {
  __shared__ float XsT[DIM][68];  // X tile transposed [d][t]
  __shared__ float Ws[DIM][68];   // W [d][e]
  const int tid = threadIdx.x;
  const int b = blockIdx.y;
  const int t0 = blockIdx.x * 64;
  const long xbase = ((long)b * T_SEQ + t0) * DIM;

  {
    const int r = tid >> 2, c0 = (tid & 3) * 16;
    float v[16];
#pragma unroll
    for (int i = 0; i < 4; i++)
      *(float4*)&v[i * 4] = *(const float4*)(X + xbase + (long)r * DIM + c0 + i * 4);
#pragma unroll
    for (int j = 0; j < 16; j++) XsT[c0 + j][r] = v[j];
    // Kh = f16(X)
    u16 h[16];
#pragma unroll
    for (int j = 0; j < 16; j++) h[j] = __builtin_bit_cast(u16, (f16)v[j]);
    u16* kd = Kh + xbase + (long)r * DIM + c0;
    *(uint4*)kd = *(uint4*)&h[0];
    *(uint4*)(kd + 8) = *(uint4*)&h[8];
    // stage W
    float wv[16];
#pragma unroll
    for (int i = 0; i < 4; i++)
      *(float4*)&wv[i * 4] = *(const float4*)(W + r * DIM + c0 + i * 4);
#pragma unroll
    for (int i = 0; i < 4; i++)
      *(float4*)&Ws[r][c0 + i * 4] = *(const float4*)&wv[i * 4];
  }
  __syncthreads();

  // Q = X @ W : wave w computes e-cols w*16..+16 for row t0+lane
  const int lane = tid & 63, w = tid >> 6;
  float acc[16];
#pragma unroll
  for (int j = 0; j < 16; j++) acc[j] = 0.0f;
  for (int d = 0; d < DIM; d++) {
    float x = XsT[d][lane];       // stride-1 across lanes: conflict-free
#pragma unroll
    for (int j = 0; j < 16; j++) acc[j] = fmaf(x, Ws[d][w * 16 + j], acc[j]);  // broadcast
  }
  u16 qh[16];
#pragma unroll
  for (int j = 0; j < 16; j++) qh[j] = __builtin_bit_cast(u16, (f16)acc[j]);
  u16* qdst = Qh + xbase + (long)lane * DIM + w * 16;
  *(uint4*)qdst = *(uint4*)&qh[0];
  *(uint4*)(qdst + 8) = *(uint4*)&qh[8];

  // Vt[b][d][t] = bf16(X[b][t][d])
  const int d = tid >> 2, tg = tid & 3;
  u16 vb[16];
#pragma unroll
  for (int j = 0; j < 16; j++) vb[j] = f2bf(XsT[d][tg * 16 + j]);
  u16* vdst = Vt + ((long)b * DIM + d) * T_SEQ + t0 + tg * 16;
  *(uint4*)vdst = *(uint4*)&vb[0];
  *(uint4*)(vdst + 8) = *(uint4*)&vb[8];
}

// ---------------- main: flash attention, no K-loop barriers ----------------
__launch_bounds__(256, 2)
__global__ void attn_kernel(const u16* __restrict__ Kh, const u16* __restrict__ Qh,
                            const u16* __restrict__ Vt, float* __restrict__ out) {
  __shared__ u16 Ps[4][QT * PSTR];       // 20480 B, wave-private P
  __shared__ float Opart[4][16 * OSTR];  // 17408 B, epilogue partials
  __shared__ float lpart[4][QT];         // 1024 B

  const int tid = threadIdx.x;
  const int lane = tid & 63;
  const int w = tid >> 6;
  const int qd = lane >> 4;
  const int ln = lane & 15;
  const int bid = blockIdx.x;
  const int b = bid & 7;                 // batch -> XCD affinity
  const int q0 = (bid >> 3) * QT;
  const long bbase = (long)b * T_SEQ * DIM;

  const u16* Khb = Kh + bbase;
  const u16* Vtb = Vt + (long)b * DIM * T_SEQ;

  // Q A-fragments pinned in registers (64 rows x 64 d)
  f16x8 aQ[4][2];
#pragma unroll
  for (int rb = 0; rb < 4; rb++)
#pragma unroll
    for (int ks = 0; ks < 2; ks++)
      aQ[rb][ks] = *(const f16x8*)(Qh + bbase + (long)(q0 + rb * 16 + ln) * DIM + ks * 32 + qd * 8);

  floatx4 O[4][4];
  float lrow[4][4];
#pragma unroll
  for (int rb = 0; rb < 4; rb++)
#pragma unroll
    for (int cd = 0; cd < 4; cd++) O[rb][cd] = (floatx4)0.0f;
#pragma unroll
  for (int rb = 0; rb < 4; rb++)
#pragma unroll
    for (int r = 0; r < 4; r++) lrow[rb][r] = 0.0f;

  u16* Pw = &Ps[w][0];

  for (int kt = 0; kt < T_SEQ / KT; kt++) {
    const int k0 = kt * KT;
    // K B-fragments straight from global (wave's own 32 keys = 2 n-blocks)
    f16x8 bK[2][2];
#pragma unroll
    for (int ct = 0; ct < 2; ct++)
#pragma unroll
      for (int ks = 0; ks < 2; ks++)
        bK[ct][ks] = *(const f16x8*)(Khb + (long)(k0 + (w * 2 + ct) * 16 + ln) * DIM + ks * 32 + qd * 8);
    // V^T B-fragments straight from global (k = wave's 32 keys)
    bf16x8 bV[4];
#pragma unroll
    for (int cd = 0; cd < 4; cd++)
      bV[cd] = *(const bf16x8*)(Vtb + (long)(cd * 16 + ln) * T_SEQ + k0 + w * 32 + qd * 8);

    // S = Q K^T (f16 single-pass), 64 q-rows x 32 keys per wave
    floatx4 S[4][2];
#pragma unroll
    for (int rb = 0; rb < 4; rb++)
#pragma unroll
      for (int ct = 0; ct < 2; ct++) S[rb][ct] = (floatx4)0.0f;
#pragma unroll
    for (int ks = 0; ks < 2; ks++)
#pragma unroll
      for (int rb = 0; rb < 4; rb++)
#pragma unroll
        for (int ct = 0; ct < 2; ct++)
          S[rb][ct] = __builtin_amdgcn_mfma_f32_16x16x32_f16(aQ[rb][ks], bK[ct][ks], S[rb][ct], 0, 0, 0);

    // P = exp(S) unnormalized (bounded: |S| <= ~26); per-lane l accumulation
#pragma unroll
    for (int rb = 0; rb < 4; rb++)
#pragma unroll
      for (int ct = 0; ct < 2; ct++)
#pragma unroll
        for (int r = 0; r < 4; r++) {
          float p = __expf(S[rb][ct][r]);
          lrow[rb][r] += p;
          Pw[(rb * 16 + qd * 4 + r) * PSTR + ct * 16 + ln] = f2bf(p);
        }
    __asm__ volatile("s_waitcnt lgkmcnt(0)" ::: "memory");  // wave-local P visibility

    // O += P V (bf16)
#pragma unroll
    for (int rb = 0; rb < 4; rb++) {
      bf16x8 aP = *(const bf16x8*)&Pw[(rb * 16 + ln) * PSTR + qd * 8];
#pragma unroll
      for (int cd = 0; cd < 4; cd++)
        O[rb][cd] = __builtin_amdgcn_mfma_f32_16x16x32_bf16(aP, bV[cd], O[rb][cd], 0, 0, 0);
    }
  }

  // l: reduce across the 16 ln-lanes of each quad
#pragma unroll
  for (int rb = 0; rb < 4; rb++)
#pragma unroll
    for (int r = 0; r < 4; r++) {
      float v = lrow[rb][r];
      v += __shfl_xor(v, 1, 64);
      v += __shfl_xor(v, 2, 64);
      v += __shfl_xor(v, 4, 64);
      v += __shfl_xor(v, 8, 64);
      lrow[rb][r] = v;
    }
  if (ln == 0) {
#pragma unroll
    for (int rb = 0; rb < 4; rb++)
#pragma unroll
      for (int r = 0; r < 4; r++)
        lpart[w][rb * 16 + qd * 4 + r] = lrow[rb][r];
  }

  // epilogue: cross-wave O reduction in 4 rounds of 16 rows
  const int erow = tid >> 4;
  const int ec0 = (tid & 15) * 4;
#pragma unroll 1
  for (int rb = 0; rb < 4; rb++) {
    __syncthreads();  // publishes lpart (round 0) / frees Opart (rounds 1+)
#pragma unroll
    for (int cd = 0; cd < 4; cd++)
#pragma unroll
      for (int r = 0; r < 4; r++)
        Opart[w][(qd * 4 + r) * OSTR + cd * 16 + ln] = O[rb][cd][r];
    __syncthreads();
    float4 s0 = *(const float4*)&Opart[0][erow * OSTR + ec0];
    float4 s1 = *(const float4*)&Opart[1][erow * OSTR + ec0];
    float4 s2 = *(const float4*)&Opart[2][erow * OSTR + ec0];
    float4 s3 = *(const float4*)&Opart[3][erow * OSTR + ec0];
    float l = lpart[0][rb * 16 + erow] + lpart[1][rb * 16 + erow] +
              lpart[2][rb * 16 + erow] + lpart[3][rb * 16 + erow];
    float inv = 1.0f / l;
    float4 o;
    o.x = (s0.x + s1.x + s2.x + s3.x) * inv;
    o.y = (s0.y + s1.y + s2.y + s3.y) * inv;
    o.z = (s0.z + s1.z + s2.z + s3.z) * inv;
    o.w = (s0.w + s1.w + s2.w + s3.w) * inv;
    *(float4*)(out + bbase + (long)(q0 + rb * 16 + erow) * DIM + ec0) = o;
  }
}

extern "C" void kernel_launch(void* const* d_in, const int* in_sizes, int n_in,
                              void* d_out, int out_size, void* d_ws, size_t ws_size,
                              hipStream_t stream) {
  const float* X = (const float*)d_in[0];
  const float* W = (const float*)d_in[1];
  float* out = (float*)d_out;
  const size_t SZ = (size_t)B_N * T_SEQ * DIM * 2;  // 4 MB per f16/bf16 array
  u16* Kh = (u16*)d_ws;
  u16* Qh = (u16*)((char*)d_ws + SZ);
  u16* Vt = (u16*)((char*)d_ws + 2 * SZ);
  prep_kernel<<<dim3(T_SEQ / 64, B_N), 256, 0, stream>>>(X, W, Kh, Qh, Vt);
  attn_kernel<<<dim3(B_N * (T_SEQ / QT)), 256, 0, stream>>>(Kh, Qh, Vt, out);
}